// Round 1
// baseline (310.175 us; speedup 1.0000x reference)
//
#include <hip/hip_runtime.h>
#include <stdint.h>

typedef __attribute__((ext_vector_type(8))) short short8;
typedef __attribute__((ext_vector_type(4))) short short4_t;
typedef __attribute__((ext_vector_type(4))) float floatx4;
typedef __attribute__((ext_vector_type(2))) float floatx2;

#define TT 128
#define DD 128

// Barrier waiting only on LDS ops: global loads/stores stay in flight.
#define BARRIER_LDS() asm volatile("s_waitcnt lgkmcnt(0)\n\ts_barrier" ::: "memory")

__device__ __forceinline__ short f2bf(float f) {
  union { float f; uint32_t u; } v; v.f = f;
  uint32_t u = v.u;
  u += 0x7fffu + ((u >> 16) & 1u);   // round-to-nearest-even
  return (short)(u >> 16);
}

__device__ __forceinline__ float sigf(float x) {
  return __builtin_amdgcn_rcpf(1.f + __expf(-x));
}
__device__ __forceinline__ float tanhf_(float x) {
  return 2.f * __builtin_amdgcn_rcpf(1.f + __expf(-2.f * x)) - 1.f;
}

// Transpose+bf16-convert all four weight matrices.
// src fp32 [K][256] (Keras layout) -> dst bf16 [256][K]
__global__ void wtrans_all(const float* __restrict__ W1, const float* __restrict__ U1,
                           const float* __restrict__ W2, const float* __restrict__ U2,
                           short* __restrict__ w1t, short* __restrict__ u1t,
                           short* __restrict__ w2t, short* __restrict__ u2t) {
  int n = blockIdx.x;   // gate column 0..255
  int k = threadIdx.x;  // 0..127
  w1t[n * 128 + k] = f2bf(W1[k * 256 + n]);
  if (k < 64) {
    u1t[n * 64 + k] = f2bf(U1[k * 256 + n]);
    w2t[n * 64 + k] = f2bf(W2[k * 256 + n]);
    u2t[n * 64 + k] = f2bf(U2[k * 256 + n]);
  }
}

// 256 blocks x 16 waves (1024 thr), 8 real batch rows/block.
// FUNCTION-SPECIALIZED waves (job = wave>>2), software-pipelined by timestep:
//   job 0 (X):  stage x + zx(t=i)   = x(i)@W1          (16 MFMA, no recurrence dep)
//   job 1 (U1): z1(t=i-1) = zx + h1(i-2)@U1, L1 elemwise -> hb1   (8 MFMA)
//   job 2 (W2): zw2(t=i-2) = h1(i-2)@W2                 (8 MFMA)
//   job 3 (U2): z2(t=i-3) = zw2 + h2(i-4)@U2, L2 elemwise -> hb2 + out (8 MFMA)
// Per-SIMD MFMA/iter stays 40 (no duplication added vs the 8-wave kernel) but
// spread over 4 waves/SIMD with 2-deep dependent chains -> MFMA pipe of one
// job overlaps VALU/LDS of the others. One lgkm-only barrier per iteration.
// All LDS exchanges are opposite-parity double-buffered (p = i&1):
//   reads:  hb1[p], hb2[p], xbuf[p], zx[1-p], zw2[1-p]
//   writes: hb1[1-p], hb2[1-p], xbuf[1-p], zx[p], zw2[p]
// zx/zw2 carry fp32 C-fragments (rows 2q,2q+1 per lane) so the accumulation
// order is BIT-IDENTICAL to the fused kernel (W-steps s0..3, then U-steps).
// MFMA 16x16x32 bf16 layouts (verified m89/m120):
//   A-frag: A[m=lane&15][k=(lane>>4)*8+j] (+32/kstep)
//   B-frag: B[k=(lane>>4)*8+j][n=lane&15]
//   C/D   : col=lane&15, row=(lane>>4)*4+reg ; br_a row-dup -> regs 0,1 = rows 2q,2q+1
__global__ __launch_bounds__(1024, 4) void lstm_fused(
    const float* __restrict__ x,
    const short* __restrict__ w1t, const short* __restrict__ u1t,
    const short* __restrict__ w2t, const short* __restrict__ u2t,
    const float* __restrict__ b1, const float* __restrict__ b2,
    float* __restrict__ out) {
  __shared__ short hb1[2][8 * 80];
  __shared__ short hb2[2][8 * 80];
  __shared__ short xbuf[2][8 * 144];
  __shared__ float zx[2][256][10];   // [par][gatecol][rowpair*2] fp32, stride 10 (bank spread)
  __shared__ float zw2[2][256][10];

  const int tid = threadIdx.x;
  const int w = tid >> 6;
  const int job = w >> 2;          // 0=X/W1, 1=U1, 2=W2, 3=U2
  const int wg = w & 3;            // 16-col slice within the 64 hidden cols
  const int lane = tid & 63;
  const int mrow = lane & 15;
  const int quad = lane >> 4;
  const int rowbase = blockIdx.x * 8;
  const int colw = wg * 16 + mrow;
  const int br_a = 2 * (mrow >> 2) + (mrow & 1);  // A-frag batch row (2x dup)

  // zero h1(-1), h2(-1) (both parities; warm-up iters read them)
  for (int idx = tid; idx < 2 * 8 * 80; idx += 1024) {
    ((short*)hb1)[idx] = 0;
    ((short*)hb2)[idx] = 0;
  }

  // x staging geometry (used by job 0 only): 256 threads x 4 consecutive floats
  const int tid2 = tid & 255;
  const int sxr = tid2 >> 5;          // batch row 0..7
  const int sxc = (tid2 & 31) * 4;    // 4-float group in D=128
  const float* xload = x + (size_t)(rowbase + sxr) * (TT * DD) + sxc;
  floatx4 xcur, xnxt;
  if (job == 0) {
    // stage x(0); prefetch x(1), x(2)
    floatx4 x0 = *(const floatx4*)xload;
    short4_t v;
#pragma unroll
    for (int j = 0; j < 4; ++j) v[j] = f2bf(x0[j]);
    *(short4_t*)&xbuf[0][sxr * 144 + sxc] = v;
    xcur = *(const floatx4*)(xload + DD);
    xnxt = *(const floatx4*)(xload + 2 * DD);
  }

  BARRIER_LDS();

  if (job == 0) {
    // ---- X job: xz precompute, zero recurrence dependence ----
    short8 wA[4][4];
#pragma unroll
    for (int g = 0; g < 4; ++g) {
      const int n = g * 4 + wg;
#pragma unroll
      for (int s = 0; s < 4; ++s)
        wA[g][s] = *(const short8*)(w1t + n * 2048 + mrow * 128 + quad * 8 + s * 32);
    }
#pragma unroll 1
    for (int i = 0; i <= TT + 2; ++i) {
      const int p = i & 1;
      if (i < TT) {
        floatx4 acc[4];
#pragma unroll
        for (int g = 0; g < 4; ++g) acc[g] = floatx4{0.f, 0.f, 0.f, 0.f};
#pragma unroll
        for (int s = 0; s < 4; ++s) {
          short8 xh = *(const short8*)&xbuf[p][br_a * 144 + (quad + 4 * s) * 8];
#pragma unroll
          for (int g = 0; g < 4; ++g)
            acc[g] = __builtin_amdgcn_mfma_f32_16x16x32_bf16(xh, wA[g][s], acc[g], 0, 0, 0);
        }
        if (i <= TT - 2) {
          // stage x(i+1); shift prefetch window to x(i+3)
          short4_t v;
#pragma unroll
          for (int j = 0; j < 4; ++j) v[j] = f2bf(xcur[j]);
          *(short4_t*)&xbuf[1 - p][sxr * 144 + sxc] = v;
          xcur = xnxt;
          const int tn = (i + 3 < TT) ? (i + 3) : (TT - 1);
          xnxt = *(const floatx4*)(xload + (size_t)tn * DD);
        }
#pragma unroll
        for (int g = 0; g < 4; ++g)
          *(floatx2*)&zx[p][g * 64 + colw][2 * quad] = floatx2{acc[g][0], acc[g][1]};
      }
      BARRIER_LDS();
    }
  } else if (job == 1) {
    // ---- U1 job: layer-1 recurrence ----
    short8 uA[4][2];
    float bias[4];
#pragma unroll
    for (int g = 0; g < 4; ++g) {
      const int n = g * 4 + wg;
#pragma unroll
      for (int s = 0; s < 2; ++s)
        uA[g][s] = *(const short8*)(u1t + n * 1024 + mrow * 64 + quad * 8 + s * 32);
      bias[g] = b1[g * 64 + colw];
    }
    float cc[2] = {0.f, 0.f};
#pragma unroll 1
    for (int i = 0; i <= TT + 2; ++i) {
      const int p = i & 1;
      if (i >= 1 && i <= TT) {
        floatx4 acc[4];
#pragma unroll
        for (int g = 0; g < 4; ++g) {
          floatx2 z = *(const floatx2*)&zx[1 - p][g * 64 + colw][2 * quad];
          acc[g] = floatx4{z[0], z[1], z[0], z[1]};
        }
#pragma unroll
        for (int s = 0; s < 2; ++s) {
          short8 hf = *(const short8*)&hb1[p][br_a * 80 + (quad + 4 * s) * 8];
#pragma unroll
          for (int g = 0; g < 4; ++g)
            acc[g] = __builtin_amdgcn_mfma_f32_16x16x32_bf16(hf, uA[g][s], acc[g], 0, 0, 0);
        }
#pragma unroll
        for (int r = 0; r < 2; ++r) {
          float ig = sigf(acc[0][r] + bias[0]);
          float fg = sigf(acc[1][r] + bias[1]);
          float gg = tanhf_(acc[2][r] + bias[2]);
          float og = sigf(acc[3][r] + bias[3]);
          float c = fg * cc[r] + ig * gg;
          cc[r] = c;
          float h = og * tanhf_(c);
          hb1[1 - p][(2 * quad + r) * 80 + colw] = f2bf(h);
        }
      }
      BARRIER_LDS();
    }
  } else if (job == 2) {
    // ---- W2 job: h1 @ W2 partial for layer 2 ----
    short8 wB[4][2];
#pragma unroll
    for (int g = 0; g < 4; ++g) {
      const int n = g * 4 + wg;
#pragma unroll
      for (int s = 0; s < 2; ++s)
        wB[g][s] = *(const short8*)(w2t + n * 1024 + mrow * 64 + quad * 8 + s * 32);
    }
#pragma unroll 1
    for (int i = 0; i <= TT + 2; ++i) {
      const int p = i & 1;
      if (i >= 2 && i <= TT + 1) {
        floatx4 acc[4];
#pragma unroll
        for (int g = 0; g < 4; ++g) acc[g] = floatx4{0.f, 0.f, 0.f, 0.f};
#pragma unroll
        for (int s = 0; s < 2; ++s) {
          short8 hf = *(const short8*)&hb1[p][br_a * 80 + (quad + 4 * s) * 8];
#pragma unroll
          for (int g = 0; g < 4; ++g)
            acc[g] = __builtin_amdgcn_mfma_f32_16x16x32_bf16(hf, wB[g][s], acc[g], 0, 0, 0);
        }
#pragma unroll
        for (int g = 0; g < 4; ++g)
          *(floatx2*)&zw2[p][g * 64 + colw][2 * quad] = floatx2{acc[g][0], acc[g][1]};
      }
      BARRIER_LDS();
    }
  } else {
    // ---- U2 job: layer-2 recurrence + output ----
    short8 uB[4][2];
    float bias[4];
#pragma unroll
    for (int g = 0; g < 4; ++g) {
      const int n = g * 4 + wg;
#pragma unroll
      for (int s = 0; s < 2; ++s)
        uB[g][s] = *(const short8*)(u2t + n * 1024 + mrow * 64 + quad * 8 + s * 32);
      bias[g] = b2[g * 64 + colw];
    }
    float cc[2] = {0.f, 0.f};
    float* outp = out + (size_t)rowbase * 8192 + colw;
#pragma unroll 1
    for (int i = 0; i <= TT + 2; ++i) {
      const int p = i & 1;
      if (i >= 3) {
        const int t = i - 3;
        floatx4 acc[4];
#pragma unroll
        for (int g = 0; g < 4; ++g) {
          floatx2 z = *(const floatx2*)&zw2[1 - p][g * 64 + colw][2 * quad];
          acc[g] = floatx4{z[0], z[1], z[0], z[1]};
        }
#pragma unroll
        for (int s = 0; s < 2; ++s) {
          short8 hf = *(const short8*)&hb2[p][br_a * 80 + (quad + 4 * s) * 8];
#pragma unroll
          for (int g = 0; g < 4; ++g)
            acc[g] = __builtin_amdgcn_mfma_f32_16x16x32_bf16(hf, uB[g][s], acc[g], 0, 0, 0);
        }
#pragma unroll
        for (int r = 0; r < 2; ++r) {
          float ig = sigf(acc[0][r] + bias[0]);
          float fg = sigf(acc[1][r] + bias[1]);
          float gg = sigf(acc[2][r] + bias[2]);
          float og = sigf(acc[3][r] + bias[3]);
          float c = fg * cc[r] + ig * gg;
          cc[r] = c;
          float h = og * sigf(c);
          hb2[1 - p][(2 * quad + r) * 80 + colw] = f2bf(h);
          outp[(size_t)(2 * quad + r) * 8192 + t * 64] = h;
        }
      }
      BARRIER_LDS();
    }
  }
}

extern "C" void kernel_launch(void* const* d_in, const int* in_sizes, int n_in,
                              void* d_out, int out_size, void* d_ws, size_t ws_size,
                              hipStream_t stream) {
  const float* x  = (const float*)d_in[0];
  const float* W1 = (const float*)d_in[1];
  const float* U1 = (const float*)d_in[2];
  const float* b1 = (const float*)d_in[3];
  const float* W2 = (const float*)d_in[4];
  const float* U2 = (const float*)d_in[5];
  const float* b2 = (const float*)d_in[6];
  float* out = (float*)d_out;

  short* w1t = (short*)d_ws;        // [256][128] bf16
  short* u1t = w1t + 32768;         // [256][64]
  short* w2t = u1t + 16384;         // [256][64]
  short* u2t = w2t + 16384;         // [256][64]

  hipLaunchKernelGGL(wtrans_all, dim3(256), dim3(128), 0, stream,
                     W1, U1, W2, U2, w1t, u1t, w2t, u2t);
  hipLaunchKernelGGL(lstm_fused, dim3(256), dim3(1024), 0, stream,
                     x, w1t, u1t, w2t, u2t, b1, b2, out);
}